// Round 1
// baseline (1119.529 us; speedup 1.0000x reference)
//
#include <hip/hip_runtime.h>

#define D 64   // hidden/output feature dim

// ---- degree count via atomics (deg buffers pre-zeroed) ----
__global__ __launch_bounds__(256) void k_deg(const int* __restrict__ src,
                                             const int* __restrict__ dst,
                                             float* __restrict__ deg_out,
                                             float* __restrict__ deg_in, int E) {
    int e = blockIdx.x * 256 + threadIdx.x;
    if (e < E) {
        atomicAdd(&deg_out[src[e]], 1.0f);
        atomicAdd(&deg_in[dst[e]], 1.0f);
    }
}

// ---- deg -> rsqrt(deg + 1)  (the +1 is the self loop) ----
__global__ __launch_bounds__(256) void k_norm(float* __restrict__ buf, int n) {
    int i = blockIdx.x * 256 + threadIdx.x;
    if (i < n) buf[i] = rsqrtf(buf[i] + 1.0f);
}

// ---- layer-1 dense: t[i][c] = dot(x[i,:128], W1[:,c]) * norm_src[i]
//      also writes agg = t (self-loop message init). One row per wave. ----
__global__ __launch_bounds__(256) void k_gemm1(const float* __restrict__ x,
                                               const float* __restrict__ W,   // [128,64] row-major
                                               const float* __restrict__ norm_src,
                                               float* __restrict__ t,
                                               float* __restrict__ agg, int N) {
    __shared__ float Ws[128 * D];
    __shared__ float xs[4][128];
    int tid = threadIdx.x;
    for (int i = tid; i < 128 * D; i += 256) Ws[i] = W[i];
    int wave = tid >> 6, lane = tid & 63;
    int row = blockIdx.x * 4 + wave;
    if (row < N) {
        xs[wave][lane]      = x[row * 128 + lane];
        xs[wave][lane + 64] = x[row * 128 + lane + 64];
    }
    __syncthreads();
    if (row >= N) return;
    float acc = 0.f;
#pragma unroll 8
    for (int k = 0; k < 128; ++k) acc += xs[wave][k] * Ws[k * D + lane];
    float v = acc * norm_src[row];
    t[row * D + lane]   = v;
    agg[row * D + lane] = v;
}

// ---- layer-2 dense (64->64). h may alias agg (in-place): row is staged to
//      LDS and __syncthreads'd before the aliased write. ----
__global__ __launch_bounds__(256) void k_gemm2(const float* h,                 // [N,64], may alias agg
                                               const float* __restrict__ W,   // [64,64]
                                               const float* __restrict__ norm_src,
                                               float* __restrict__ t,
                                               float* agg, int N) {
    __shared__ float Ws[D * D];
    __shared__ float hs[4][D];
    int tid = threadIdx.x;
    for (int i = tid; i < D * D; i += 256) Ws[i] = W[i];
    int wave = tid >> 6, lane = tid & 63;
    int row = blockIdx.x * 4 + wave;
    if (row < N) hs[wave][lane] = h[row * D + lane];
    __syncthreads();
    if (row >= N) return;
    float acc = 0.f;
#pragma unroll 8
    for (int k = 0; k < D; ++k) acc += hs[wave][k] * Ws[k * D + lane];
    float v = acc * norm_src[row];
    t[row * D + lane]   = v;
    agg[row * D + lane] = v;
}

// ---- scatter-aggregate: one wave per edge, lane = channel ----
__global__ __launch_bounds__(256) void k_edge(const int* __restrict__ src,
                                              const int* __restrict__ dst,
                                              const float* __restrict__ t,
                                              float* __restrict__ agg, int E) {
    long long gid = (long long)blockIdx.x * 256 + threadIdx.x;
    int e = (int)(gid >> 6);
    int c = (int)(gid & 63);
    if (e < E) {
        int s = src[e], d = dst[e];
        atomicAdd(&agg[d * D + c], t[s * D + c]);
    }
}

// ---- epilogue: out = (optional relu)(agg * norm_dst + b). out may alias agg. ----
__global__ __launch_bounds__(256) void k_post(const float* __restrict__ agg,
                                              const float* __restrict__ norm_dst,
                                              const float* __restrict__ b,
                                              float* out, int N, int do_relu) {
    int idx = blockIdx.x * 256 + threadIdx.x;
    if (idx < N * D) {
        int i = idx >> 6, c = idx & 63;
        float v = fmaf(agg[idx], norm_dst[i], b[c]);
        if (do_relu) v = fmaxf(v, 0.f);
        out[idx] = v;
    }
}

extern "C" void kernel_launch(void* const* d_in, const int* in_sizes, int n_in,
                              void* d_out, int out_size, void* d_ws, size_t ws_size,
                              hipStream_t stream) {
    const float* x   = (const float*)d_in[0];
    const int*   src = (const int*)d_in[1];
    const int*   dst = (const int*)d_in[2];
    const float* W1  = (const float*)d_in[3];
    const float* b1  = (const float*)d_in[4];
    const float* W2  = (const float*)d_in[5];
    const float* b2  = (const float*)d_in[6];
    float* out = (float*)d_out;

    const int N = in_sizes[0] / 128;
    const int E = in_sizes[1];

    // workspace layout (floats): norm_src[N] | norm_dst[N] | t[N*64] | agg[N*64]
    float* ws       = (float*)d_ws;
    float* norm_src = ws;
    float* norm_dst = ws + N;
    float* t        = ws + 2 * (long long)N;
    float* agg      = t + (long long)N * D;

    // zero the degree accumulators (ws is poisoned each call)
    hipMemsetAsync(norm_src, 0, (size_t)2 * N * sizeof(float), stream);

    k_deg<<<(E + 255) / 256, 256, 0, stream>>>(src, dst, norm_src, norm_dst, E);
    k_norm<<<(2 * N + 255) / 256, 256, 0, stream>>>(norm_src, 2 * N);

    // layer 1
    k_gemm1<<<(N + 3) / 4, 256, 0, stream>>>(x, W1, norm_src, t, agg, N);
    {
        long long tot = (long long)E * 64;
        k_edge<<<(int)((tot + 255) / 256), 256, 0, stream>>>(src, dst, t, agg, E);
    }
    k_post<<<(N * D + 255) / 256, 256, 0, stream>>>(agg, norm_dst, b1, agg, N, 1); // h in-place

    // layer 2
    k_gemm2<<<(N + 3) / 4, 256, 0, stream>>>(agg, W2, norm_src, t, agg, N);
    {
        long long tot = (long long)E * 64;
        k_edge<<<(int)((tot + 255) / 256), 256, 0, stream>>>(src, dst, t, agg, E);
    }
    k_post<<<(N * D + 255) / 256, 256, 0, stream>>>(agg, norm_dst, b2, out, N, 0);
}

// Round 2
// 621.785 us; speedup vs baseline: 1.8005x; 1.8005x over previous
//
#include <hip/hip_runtime.h>

#define D 64   // hidden/output feature dim

// ---------------------------------------------------------------------------
// CSR build: count -> exclusive scan (3-kernel hierarchical) -> scatter
// ---------------------------------------------------------------------------

__global__ __launch_bounds__(256) void k_count(const int* __restrict__ src,
                                               const int* __restrict__ dst,
                                               int* __restrict__ out_cnt,
                                               int* __restrict__ in_cnt, int E) {
    int e = blockIdx.x * 256 + threadIdx.x;
    if (e < E) {
        atomicAdd(&out_cnt[src[e]], 1);
        atomicAdd(&in_cnt[dst[e]], 1);
    }
}

// block scans 1024 elements (256 thr x 4 items), writes exclusive-within-block
// prefix to out[] and the block total to partials[blockIdx].
__global__ __launch_bounds__(256) void k_scan1(const int* __restrict__ in,
                                               int* __restrict__ out,
                                               int* __restrict__ partials, int n) {
    __shared__ int s[256];
    int tid = threadIdx.x;
    int base = blockIdx.x * 1024 + tid * 4;
    int v[4];
#pragma unroll
    for (int j = 0; j < 4; ++j) v[j] = (base + j < n) ? in[base + j] : 0;
    int l1 = v[0] + v[1];
    int l2 = l1 + v[2];
    int total = l2 + v[3];
    s[tid] = total;
    __syncthreads();
    for (int off = 1; off < 256; off <<= 1) {
        int add = (tid >= off) ? s[tid - off] : 0;
        __syncthreads();
        s[tid] += add;
        __syncthreads();
    }
    int excl = s[tid] - total;  // exclusive sum of preceding threads' totals
    if (base + 0 < n) out[base + 0] = excl;
    if (base + 1 < n) out[base + 1] = excl + v[0];
    if (base + 2 < n) out[base + 2] = excl + l1;
    if (base + 3 < n) out[base + 3] = excl + l2;
    if (tid == 255) partials[blockIdx.x] = s[255];
}

__global__ void k_scan2(int* __restrict__ partials, int B) {
    if (threadIdx.x == 0) {
        int run = 0;
        for (int i = 0; i < B; ++i) {
            int tmp = partials[i];
            partials[i] = run;
            run += tmp;
        }
    }
}

__global__ __launch_bounds__(256) void k_scan3(int* __restrict__ out,
                                               const int* __restrict__ partials, int n) {
    int off = partials[blockIdx.x];
    int base = blockIdx.x * 1024 + threadIdx.x * 4;
#pragma unroll
    for (int j = 0; j < 4; ++j)
        if (base + j < n) out[base + j] += off;
}

__global__ __launch_bounds__(256) void k_scatter(const int* __restrict__ src,
                                                 const int* __restrict__ dst,
                                                 const int* __restrict__ row_ptr,
                                                 int* __restrict__ cursor,
                                                 int* __restrict__ csr, int E) {
    int e = blockIdx.x * 256 + threadIdx.x;
    if (e < E) {
        int d = dst[e];
        int p = atomicAdd(&cursor[d], 1);
        csr[row_ptr[d] + p] = src[e];
    }
}

// ---- counts -> rsqrt(cnt + 1)  (the +1 is the self loop) ----
__global__ __launch_bounds__(256) void k_norm(const int* __restrict__ cnt,
                                              float* __restrict__ nrm, int n) {
    int i = blockIdx.x * 256 + threadIdx.x;
    if (i < n) nrm[i] = rsqrtf((float)cnt[i] + 1.0f);
}

// ---------------------------------------------------------------------------
// dense: t[i][c] = dot(h[i,:K], W[:,c]) * norm_src[i].  One row per wave.
// ---------------------------------------------------------------------------
template <int K>
__global__ __launch_bounds__(256) void k_gemm(const float* __restrict__ h,
                                              const float* __restrict__ W,   // [K,64] row-major
                                              const float* __restrict__ norm_src,
                                              float* __restrict__ t, int N) {
    __shared__ float Ws[K * D];
    __shared__ float hs[4][K];
    int tid = threadIdx.x;
    for (int i = tid; i < K * D; i += 256) Ws[i] = W[i];
    int wave = tid >> 6, lane = tid & 63;
    int row = blockIdx.x * 4 + wave;
    if (row < N) {
#pragma unroll
        for (int j = 0; j < K / 64; ++j)
            hs[wave][lane + j * 64] = h[row * K + lane + j * 64];
    }
    __syncthreads();
    if (row >= N) return;
    float acc = 0.f;
#pragma unroll 8
    for (int k = 0; k < K; ++k) acc += hs[wave][k] * Ws[k * D + lane];
    t[row * D + lane] = acc * norm_src[row];
}

// ---------------------------------------------------------------------------
// gather-aggregate + fused epilogue: one wave per dst node, lane = channel.
// self-loop message = t[i] (src==dst==i), used as accumulator init.
// ---------------------------------------------------------------------------
__global__ __launch_bounds__(256) void k_agg(const int* __restrict__ row_ptr,
                                             const int* __restrict__ cnt,
                                             const int* __restrict__ csr,
                                             const float* __restrict__ t,
                                             const float* __restrict__ norm_dst,
                                             const float* __restrict__ bias,
                                             float* __restrict__ out, int N, int do_relu) {
    int wave = threadIdx.x >> 6, lane = threadIdx.x & 63;
    int i = blockIdx.x * 4 + wave;
    if (i >= N) return;
    int start = row_ptr[i], c = cnt[i];
    float acc = t[i * D + lane];  // self loop
    int j = 0;
    for (; j + 4 <= c; j += 4) {
        int s0 = csr[start + j];
        int s1 = csr[start + j + 1];
        int s2 = csr[start + j + 2];
        int s3 = csr[start + j + 3];
        float a0 = t[s0 * D + lane];
        float a1 = t[s1 * D + lane];
        float a2 = t[s2 * D + lane];
        float a3 = t[s3 * D + lane];
        acc += (a0 + a1) + (a2 + a3);
    }
    for (; j < c; ++j) acc += t[csr[start + j] * D + lane];
    float v = fmaf(acc, norm_dst[i], bias[lane]);
    if (do_relu) v = fmaxf(v, 0.f);
    out[i * D + lane] = v;
}

extern "C" void kernel_launch(void* const* d_in, const int* in_sizes, int n_in,
                              void* d_out, int out_size, void* d_ws, size_t ws_size,
                              hipStream_t stream) {
    const float* x   = (const float*)d_in[0];
    const int*   src = (const int*)d_in[1];
    const int*   dst = (const int*)d_in[2];
    const float* W1  = (const float*)d_in[3];
    const float* b1  = (const float*)d_in[4];
    const float* W2  = (const float*)d_in[5];
    const float* b2  = (const float*)d_in[6];
    float* out = (float*)d_out;

    const int N = in_sizes[0] / 128;
    const int E = in_sizes[1];

    // workspace layout (4-byte units):
    int*   cnt_out  = (int*)d_ws;              // N
    int*   cnt_in   = cnt_out + N;             // N   (contiguous with cnt_out)
    int*   cursor   = cnt_in + N;              // N   (contiguous: one memset covers all 3)
    int*   row_ptr  = cursor + N;              // N
    int*   partials = row_ptr + N;             // 1024
    float* norm_src = (float*)(partials + 1024); // N
    float* norm_dst = norm_src + N;            // N   (contiguous with norm_src)
    float* t        = norm_dst + N;            // N*64
    float* h        = t + (long long)N * D;    // N*64
    int*   csr      = (int*)(h + (long long)N * D); // E

    const int B = (N + 1023) / 1024;  // scan blocks

    hipMemsetAsync(cnt_out, 0, (size_t)3 * N * sizeof(int), stream);

    k_count<<<(E + 255) / 256, 256, 0, stream>>>(src, dst, cnt_out, cnt_in, E);
    k_norm<<<(2 * N + 255) / 256, 256, 0, stream>>>(cnt_out, norm_src, 2 * N); // both arrays

    k_scan1<<<B, 256, 0, stream>>>(cnt_in, row_ptr, partials, N);
    k_scan2<<<1, 64, 0, stream>>>(partials, B);
    k_scan3<<<B, 256, 0, stream>>>(row_ptr, partials, N);
    k_scatter<<<(E + 255) / 256, 256, 0, stream>>>(src, dst, row_ptr, cursor, csr, E);

    // layer 1: t = (x W1) * norm_src ; h = relu(agg * norm_dst + b1)
    k_gemm<128><<<(N + 3) / 4, 256, 0, stream>>>(x, W1, norm_src, t, N);
    k_agg<<<(N + 3) / 4, 256, 0, stream>>>(row_ptr, cnt_in, csr, t, norm_dst, b1, h, N, 1);

    // layer 2: t = (h W2) * norm_src ; out = agg * norm_dst + b2
    k_gemm<64><<<(N + 3) / 4, 256, 0, stream>>>(h, W2, norm_src, t, N);
    k_agg<<<(N + 3) / 4, 256, 0, stream>>>(row_ptr, cnt_in, csr, t, norm_dst, b2, out, N, 0);
}

// Round 4
// 550.284 us; speedup vs baseline: 2.0345x; 1.1299x over previous
//
#include <hip/hip_runtime.h>

#define D 64         // hidden/output feature dim
#define SLICE 25000  // histogram nodes per slice (100 KB LDS)

// ---------------------------------------------------------------------------
// LDS-sliced degree histogram (replaces R2's k_count global-atomic storm).
// grid = (32, ceil(N/SLICE), 2); z=0 counts src -> cnt_out, z=1 dst -> cnt_in.
// Each (x,y,z) block reads a strided chunk of the edge array (int4), counts
// the nodes falling in its slice into LDS, then merges with coalesced,
// zero-skipped global atomics.
// ---------------------------------------------------------------------------
__global__ __launch_bounds__(256) void k_hist(const int* __restrict__ src,
                                              const int* __restrict__ dst,
                                              int* __restrict__ cnt_out,
                                              int* __restrict__ cnt_in,
                                              int E, int N) {
    __shared__ int h[SLICE];
    const int* idx = blockIdx.z ? dst : src;
    int* cnt       = blockIdx.z ? cnt_in : cnt_out;
    int lo = blockIdx.y * SLICE;
    int hi = min(lo + SLICE, N);
    int len = hi - lo;
    for (int i = threadIdx.x; i < len; i += 256) h[i] = 0;
    __syncthreads();

    const int E4 = E >> 2;
    const int4* idx4 = (const int4*)idx;
    int stride = gridDim.x * 256;
    for (int i = blockIdx.x * 256 + threadIdx.x; i < E4; i += stride) {
        int4 v = idx4[i];
        if (v.x >= lo && v.x < hi) atomicAdd(&h[v.x - lo], 1);
        if (v.y >= lo && v.y < hi) atomicAdd(&h[v.y - lo], 1);
        if (v.z >= lo && v.z < hi) atomicAdd(&h[v.z - lo], 1);
        if (v.w >= lo && v.w < hi) atomicAdd(&h[v.w - lo], 1);
    }
    // tail (E % 4), handled by x==0 blocks
    if (blockIdx.x == 0) {
        int e = E4 * 4 + threadIdx.x;
        if (e < E) {
            int v = idx[e];
            if (v >= lo && v < hi) atomicAdd(&h[v - lo], 1);
        }
    }
    __syncthreads();
    for (int i = threadIdx.x; i < len; i += 256) {
        int c = h[i];
        if (c) atomicAdd(&cnt[lo + i], c);
    }
}

// ---- counts -> rsqrt(cnt + 1)  (the +1 is the self loop) ----
__global__ __launch_bounds__(256) void k_norm(const int* __restrict__ cnt,
                                              float* __restrict__ nrm, int n) {
    int i = blockIdx.x * 256 + threadIdx.x;
    if (i < n) nrm[i] = rsqrtf((float)cnt[i] + 1.0f);
}

// ---------------------------------------------------------------------------
// exclusive scan of cnt_in -> row_ptr  (3-kernel hierarchical) — R2 verbatim
// ---------------------------------------------------------------------------
__global__ __launch_bounds__(256) void k_scan1(const int* __restrict__ in,
                                               int* __restrict__ out,
                                               int* __restrict__ partials, int n) {
    __shared__ int s[256];
    int tid = threadIdx.x;
    int base = blockIdx.x * 1024 + tid * 4;
    int v[4];
#pragma unroll
    for (int j = 0; j < 4; ++j) v[j] = (base + j < n) ? in[base + j] : 0;
    int l1 = v[0] + v[1];
    int l2 = l1 + v[2];
    int total = l2 + v[3];
    s[tid] = total;
    __syncthreads();
    for (int off = 1; off < 256; off <<= 1) {
        int add = (tid >= off) ? s[tid - off] : 0;
        __syncthreads();
        s[tid] += add;
        __syncthreads();
    }
    int excl = s[tid] - total;  // exclusive sum of preceding threads' totals
    if (base + 0 < n) out[base + 0] = excl;
    if (base + 1 < n) out[base + 1] = excl + v[0];
    if (base + 2 < n) out[base + 2] = excl + l1;
    if (base + 3 < n) out[base + 3] = excl + l2;
    if (tid == 255) partials[blockIdx.x] = s[255];
}

__global__ void k_scan2(int* __restrict__ partials, int B) {
    if (threadIdx.x == 0) {
        int run = 0;
        for (int i = 0; i < B; ++i) {
            int tmp = partials[i];
            partials[i] = run;
            run += tmp;
        }
    }
}

__global__ __launch_bounds__(256) void k_scan3(int* __restrict__ out,
                                               const int* __restrict__ partials, int n) {
    int off = partials[blockIdx.x];
    int base = blockIdx.x * 1024 + threadIdx.x * 4;
#pragma unroll
    for (int j = 0; j < 4; ++j)
        if (base + j < n) out[base + j] += off;
}

__global__ __launch_bounds__(256) void k_scatter(const int* __restrict__ src,
                                                 const int* __restrict__ dst,
                                                 const int* __restrict__ row_ptr,
                                                 int* __restrict__ cursor,
                                                 int* __restrict__ csr, int E) {
    int e = blockIdx.x * 256 + threadIdx.x;
    if (e < E) {
        int d = dst[e];
        int p = atomicAdd(&cursor[d], 1);
        csr[row_ptr[d] + p] = src[e];
    }
}

// ---------------------------------------------------------------------------
// dense: t[i][c] = dot(h[i,:K], W[:,c]) * norm_src[i].  One row per wave.
// ---------------------------------------------------------------------------
template <int K>
__global__ __launch_bounds__(256) void k_gemm(const float* __restrict__ h,
                                              const float* __restrict__ W,   // [K,64] row-major
                                              const float* __restrict__ norm_src,
                                              float* __restrict__ t, int N) {
    __shared__ float Ws[K * D];
    __shared__ float hs[4][K];
    int tid = threadIdx.x;
    for (int i = tid; i < K * D; i += 256) Ws[i] = W[i];
    int wave = tid >> 6, lane = tid & 63;
    int row = blockIdx.x * 4 + wave;
    if (row < N) {
#pragma unroll
        for (int j = 0; j < K / 64; ++j)
            hs[wave][lane + j * 64] = h[row * K + lane + j * 64];
    }
    __syncthreads();
    if (row >= N) return;
    float acc = 0.f;
#pragma unroll 8
    for (int k = 0; k < K; ++k) acc += hs[wave][k] * Ws[k * D + lane];
    t[row * D + lane] = acc * norm_src[row];
}

// ---------------------------------------------------------------------------
// gather-aggregate + fused epilogue: one wave per dst node, lane = channel.
// self-loop message = t[i], used as accumulator init.
// ---------------------------------------------------------------------------
__global__ __launch_bounds__(256) void k_agg(const int* __restrict__ row_ptr,
                                             const int* __restrict__ cnt,
                                             const int* __restrict__ csr,
                                             const float* __restrict__ t,
                                             const float* __restrict__ norm_dst,
                                             const float* __restrict__ bias,
                                             float* __restrict__ out, int N, int do_relu) {
    int wave = threadIdx.x >> 6, lane = threadIdx.x & 63;
    int i = blockIdx.x * 4 + wave;
    if (i >= N) return;
    int start = row_ptr[i], c = cnt[i];
    float acc = t[i * D + lane];  // self loop
    int j = 0;
    for (; j + 4 <= c; j += 4) {
        int s0 = csr[start + j];
        int s1 = csr[start + j + 1];
        int s2 = csr[start + j + 2];
        int s3 = csr[start + j + 3];
        float a0 = t[s0 * D + lane];
        float a1 = t[s1 * D + lane];
        float a2 = t[s2 * D + lane];
        float a3 = t[s3 * D + lane];
        acc += (a0 + a1) + (a2 + a3);
    }
    for (; j < c; ++j) acc += t[csr[start + j] * D + lane];
    float v = fmaf(acc, norm_dst[i], bias[lane]);
    if (do_relu) v = fmaxf(v, 0.f);
    out[i * D + lane] = v;
}

extern "C" void kernel_launch(void* const* d_in, const int* in_sizes, int n_in,
                              void* d_out, int out_size, void* d_ws, size_t ws_size,
                              hipStream_t stream) {
    const float* x   = (const float*)d_in[0];
    const int*   src = (const int*)d_in[1];
    const int*   dst = (const int*)d_in[2];
    const float* W1  = (const float*)d_in[3];
    const float* b1  = (const float*)d_in[4];
    const float* W2  = (const float*)d_in[5];
    const float* b2  = (const float*)d_in[6];
    float* out = (float*)d_out;

    const int N = in_sizes[0] / 128;
    const int E = in_sizes[1];

    // workspace layout (4-byte units) — identical to R2:
    int*   cnt_out  = (int*)d_ws;              // N
    int*   cnt_in   = cnt_out + N;             // N   (contiguous with cnt_out)
    int*   cursor   = cnt_in + N;              // N   (contiguous: one memset covers all 3)
    int*   row_ptr  = cursor + N;              // N
    int*   partials = row_ptr + N;             // 1024
    float* norm_src = (float*)(partials + 1024); // N
    float* norm_dst = norm_src + N;            // N   (contiguous with norm_src)
    float* t        = norm_dst + N;            // N*64
    float* h        = t + (long long)N * D;    // N*64
    int*   csr      = (int*)(h + (long long)N * D); // E

    const int B = (N + 1023) / 1024;  // scan blocks
    const int NS = (N + SLICE - 1) / SLICE;

    hipMemsetAsync(cnt_out, 0, (size_t)3 * N * sizeof(int), stream);

    k_hist<<<dim3(32, NS, 2), 256, 0, stream>>>(src, dst, cnt_out, cnt_in, E, N);
    k_norm<<<(2 * N + 255) / 256, 256, 0, stream>>>(cnt_out, norm_src, 2 * N); // both arrays

    k_scan1<<<B, 256, 0, stream>>>(cnt_in, row_ptr, partials, N);
    k_scan2<<<1, 64, 0, stream>>>(partials, B);
    k_scan3<<<B, 256, 0, stream>>>(row_ptr, partials, N);
    k_scatter<<<(E + 255) / 256, 256, 0, stream>>>(src, dst, row_ptr, cursor, csr, E);

    // layer 1: t = (x W1) * norm_src ; h = relu(agg * norm_dst + b1)
    k_gemm<128><<<(N + 3) / 4, 256, 0, stream>>>(x, W1, norm_src, t, N);
    k_agg<<<(N + 3) / 4, 256, 0, stream>>>(row_ptr, cnt_in, csr, t, norm_dst, b1, h, N, 1);

    // layer 2: t = (h W2) * norm_src ; out = agg * norm_dst + b2
    k_gemm<64><<<(N + 3) / 4, 256, 0, stream>>>(h, W2, norm_src, t, N);
    k_agg<<<(N + 3) / 4, 256, 0, stream>>>(row_ptr, cnt_in, csr, t, norm_dst, b2, out, N, 0);
}

// Round 5
// 443.618 us; speedup vs baseline: 2.5236x; 1.2404x over previous
//
#include <hip/hip_runtime.h>

#define D 64         // hidden/output feature dim
#define SLICE 25000  // histogram nodes per slice (100 KB LDS)

typedef __attribute__((ext_vector_type(8))) short short8;   // 8 bf16 (4 VGPRs)
typedef __attribute__((ext_vector_type(4))) float floatx4;  // 4 fp32 acc

// ---------------------------------------------------------------------------
// LDS-sliced degree histogram (R4 verbatim).
// ---------------------------------------------------------------------------
__global__ __launch_bounds__(256) void k_hist(const int* __restrict__ src,
                                              const int* __restrict__ dst,
                                              int* __restrict__ cnt_out,
                                              int* __restrict__ cnt_in,
                                              int E, int N) {
    __shared__ int h[SLICE];
    const int* idx = blockIdx.z ? dst : src;
    int* cnt       = blockIdx.z ? cnt_in : cnt_out;
    int lo = blockIdx.y * SLICE;
    int hi = min(lo + SLICE, N);
    int len = hi - lo;
    for (int i = threadIdx.x; i < len; i += 256) h[i] = 0;
    __syncthreads();

    const int E4 = E >> 2;
    const int4* idx4 = (const int4*)idx;
    int stride = gridDim.x * 256;
    for (int i = blockIdx.x * 256 + threadIdx.x; i < E4; i += stride) {
        int4 v = idx4[i];
        if (v.x >= lo && v.x < hi) atomicAdd(&h[v.x - lo], 1);
        if (v.y >= lo && v.y < hi) atomicAdd(&h[v.y - lo], 1);
        if (v.z >= lo && v.z < hi) atomicAdd(&h[v.z - lo], 1);
        if (v.w >= lo && v.w < hi) atomicAdd(&h[v.w - lo], 1);
    }
    if (blockIdx.x == 0) {
        int e = E4 * 4 + threadIdx.x;
        if (e < E) {
            int v = idx[e];
            if (v >= lo && v < hi) atomicAdd(&h[v - lo], 1);
        }
    }
    __syncthreads();
    for (int i = threadIdx.x; i < len; i += 256) {
        int c = h[i];
        if (c) atomicAdd(&cnt[lo + i], c);
    }
}

// ---- counts -> rsqrt(cnt + 1)  (the +1 is the self loop) ----
__global__ __launch_bounds__(256) void k_norm(const int* __restrict__ cnt,
                                              float* __restrict__ nrm, int n) {
    int i = blockIdx.x * 256 + threadIdx.x;
    if (i < n) nrm[i] = rsqrtf((float)cnt[i] + 1.0f);
}

// ---------------------------------------------------------------------------
// exclusive scan of cnt_in -> row_ptr  (R2/R4 verbatim)
// ---------------------------------------------------------------------------
__global__ __launch_bounds__(256) void k_scan1(const int* __restrict__ in,
                                               int* __restrict__ out,
                                               int* __restrict__ partials, int n) {
    __shared__ int s[256];
    int tid = threadIdx.x;
    int base = blockIdx.x * 1024 + tid * 4;
    int v[4];
#pragma unroll
    for (int j = 0; j < 4; ++j) v[j] = (base + j < n) ? in[base + j] : 0;
    int l1 = v[0] + v[1];
    int l2 = l1 + v[2];
    int total = l2 + v[3];
    s[tid] = total;
    __syncthreads();
    for (int off = 1; off < 256; off <<= 1) {
        int add = (tid >= off) ? s[tid - off] : 0;
        __syncthreads();
        s[tid] += add;
        __syncthreads();
    }
    int excl = s[tid] - total;
    if (base + 0 < n) out[base + 0] = excl;
    if (base + 1 < n) out[base + 1] = excl + v[0];
    if (base + 2 < n) out[base + 2] = excl + l1;
    if (base + 3 < n) out[base + 3] = excl + l2;
    if (tid == 255) partials[blockIdx.x] = s[255];
}

__global__ void k_scan2(int* __restrict__ partials, int B) {
    if (threadIdx.x == 0) {
        int run = 0;
        for (int i = 0; i < B; ++i) {
            int tmp = partials[i];
            partials[i] = run;
            run += tmp;
        }
    }
}

__global__ __launch_bounds__(256) void k_scan3(int* __restrict__ out,
                                               const int* __restrict__ partials, int n) {
    int off = partials[blockIdx.x];
    int base = blockIdx.x * 1024 + threadIdx.x * 4;
#pragma unroll
    for (int j = 0; j < 4; ++j)
        if (base + j < n) out[base + j] += off;
}

__global__ __launch_bounds__(256) void k_scatter(const int* __restrict__ src,
                                                 const int* __restrict__ dst,
                                                 const int* __restrict__ row_ptr,
                                                 int* __restrict__ cursor,
                                                 int* __restrict__ csr, int E) {
    int e = blockIdx.x * 256 + threadIdx.x;
    if (e < E) {
        int d = dst[e];
        int p = atomicAdd(&cursor[d], 1);
        csr[row_ptr[d] + p] = src[e];
    }
}

// ---------------------------------------------------------------------------
// MFMA dense layer via split-bf16: t[i][c] = dot(h[i,:K], W[:,c]) * norm_src[i]
// x ≈ hi + lo (two bf16), W likewise; D = hi·hi + hi·lo + lo·hi in fp32 accum
// (error ~2^-16 relative — fp32-class).  One wave = 16 rows x 64 cols;
// block = 4 waves = 64 rows.  W split+repacked in LDS so each B fragment is
// one ds_read_b128.
// Fragment maps (m89/m120-verified): A[m=lane&15][k=quad*8+j];
// B[k=quad*8+j][n=lane&15]; C/D col=lane&15, row=quad*4+reg.
// ---------------------------------------------------------------------------
template <int K>
__global__ __launch_bounds__(256) void k_gemm_mfma(const float* __restrict__ hsrc,
                                                   const float* __restrict__ W,   // [K,64] row-major
                                                   const float* __restrict__ norm_src,
                                                   float* __restrict__ t, int N) {
    constexpr int NKI = K / 32;                 // MFMA K-steps
    __shared__ short Whi[NKI * 2048];           // [ki][ct][n][q][j]
    __shared__ short Wlo[NKI * 2048];
    int tid = threadIdx.x;

    // stage + split + repack W into fragment order
    for (int f = tid; f < K * 64; f += 256) {
        int n  = f & 15;
        int j  = (f >> 4) & 7;
        int q  = (f >> 7) & 3;
        int ct = (f >> 9) & 3;
        int ki = f >> 11;
        int k = ki * 32 + q * 8 + j;
        int c = ct * 16 + n;
        float w = W[k * 64 + c];
        unsigned u = __float_as_uint(w);
        float l = w - __uint_as_float(u & 0xffff0000u);
        int idx = (((ki * 4 + ct) * 16 + n) * 4 + q) * 8 + j;
        Whi[idx] = (short)(u >> 16);
        Wlo[idx] = (short)(__float_as_uint(l) >> 16);
    }
    __syncthreads();

    int wave = tid >> 6, lane = tid & 63;
    int q = lane >> 4, n = lane & 15;
    int r0 = blockIdx.x * 64 + wave * 16;
    int rowc = min(r0 + n, N - 1);              // clamped A-row for loads

    floatx4 acc[4] = {{0.f,0.f,0.f,0.f},{0.f,0.f,0.f,0.f},
                      {0.f,0.f,0.f,0.f},{0.f,0.f,0.f,0.f}};

    for (int ki = 0; ki < NKI; ++ki) {
        const float* ap = hsrc + (long long)rowc * K + ki * 32 + q * 8;
        float4 a0 = *(const float4*)ap;
        float4 a1 = *(const float4*)(ap + 4);
        float av[8] = {a0.x, a0.y, a0.z, a0.w, a1.x, a1.y, a1.z, a1.w};
        short8 ahi, alo;
#pragma unroll
        for (int j = 0; j < 8; ++j) {
            unsigned u = __float_as_uint(av[j]);
            float l = av[j] - __uint_as_float(u & 0xffff0000u);
            ahi[j] = (short)(u >> 16);
            alo[j] = (short)(__float_as_uint(l) >> 16);
        }
#pragma unroll
        for (int ct = 0; ct < 4; ++ct) {
            int bidx = (((ki * 4 + ct) * 16 + n) * 4 + q) * 8;
            short8 bhi = *(const short8*)&Whi[bidx];
            short8 blo = *(const short8*)&Wlo[bidx];
            acc[ct] = __builtin_amdgcn_mfma_f32_16x16x32_bf16(ahi, bhi, acc[ct], 0, 0, 0);
            acc[ct] = __builtin_amdgcn_mfma_f32_16x16x32_bf16(ahi, blo, acc[ct], 0, 0, 0);
            acc[ct] = __builtin_amdgcn_mfma_f32_16x16x32_bf16(alo, bhi, acc[ct], 0, 0, 0);
        }
    }

    // epilogue: C/D col = n, row = q*4 + reg
#pragma unroll
    for (int reg = 0; reg < 4; ++reg) {
        int orow = r0 + q * 4 + reg;
        if (orow < N) {
            float nrm = norm_src[orow];
#pragma unroll
            for (int ct = 0; ct < 4; ++ct)
                t[(long long)orow * 64 + ct * 16 + n] = acc[ct][reg] * nrm;
        }
    }
}

// ---------------------------------------------------------------------------
// gather-aggregate + fused epilogue (R4 verbatim)
// ---------------------------------------------------------------------------
__global__ __launch_bounds__(256) void k_agg(const int* __restrict__ row_ptr,
                                             const int* __restrict__ cnt,
                                             const int* __restrict__ csr,
                                             const float* __restrict__ t,
                                             const float* __restrict__ norm_dst,
                                             const float* __restrict__ bias,
                                             float* __restrict__ out, int N, int do_relu) {
    int wave = threadIdx.x >> 6, lane = threadIdx.x & 63;
    int i = blockIdx.x * 4 + wave;
    if (i >= N) return;
    int start = row_ptr[i], c = cnt[i];
    float acc = t[i * D + lane];  // self loop
    int j = 0;
    for (; j + 4 <= c; j += 4) {
        int s0 = csr[start + j];
        int s1 = csr[start + j + 1];
        int s2 = csr[start + j + 2];
        int s3 = csr[start + j + 3];
        float a0 = t[s0 * D + lane];
        float a1 = t[s1 * D + lane];
        float a2 = t[s2 * D + lane];
        float a3 = t[s3 * D + lane];
        acc += (a0 + a1) + (a2 + a3);
    }
    for (; j < c; ++j) acc += t[csr[start + j] * D + lane];
    float v = fmaf(acc, norm_dst[i], bias[lane]);
    if (do_relu) v = fmaxf(v, 0.f);
    out[i * D + lane] = v;
}

extern "C" void kernel_launch(void* const* d_in, const int* in_sizes, int n_in,
                              void* d_out, int out_size, void* d_ws, size_t ws_size,
                              hipStream_t stream) {
    const float* x   = (const float*)d_in[0];
    const int*   src = (const int*)d_in[1];
    const int*   dst = (const int*)d_in[2];
    const float* W1  = (const float*)d_in[3];
    const float* b1  = (const float*)d_in[4];
    const float* W2  = (const float*)d_in[5];
    const float* b2  = (const float*)d_in[6];
    float* out = (float*)d_out;

    const int N = in_sizes[0] / 128;
    const int E = in_sizes[1];

    // workspace layout (4-byte units) — identical to R4:
    int*   cnt_out  = (int*)d_ws;              // N
    int*   cnt_in   = cnt_out + N;             // N
    int*   cursor   = cnt_in + N;              // N   (one memset covers all 3)
    int*   row_ptr  = cursor + N;              // N
    int*   partials = row_ptr + N;             // 1024
    float* norm_src = (float*)(partials + 1024); // N
    float* norm_dst = norm_src + N;            // N
    float* t        = norm_dst + N;            // N*64
    float* h        = t + (long long)N * D;    // N*64
    int*   csr      = (int*)(h + (long long)N * D); // E

    const int B = (N + 1023) / 1024;  // scan blocks
    const int NS = (N + SLICE - 1) / SLICE;

    hipMemsetAsync(cnt_out, 0, (size_t)3 * N * sizeof(int), stream);

    k_hist<<<dim3(32, NS, 2), 256, 0, stream>>>(src, dst, cnt_out, cnt_in, E, N);
    k_norm<<<(2 * N + 255) / 256, 256, 0, stream>>>(cnt_out, norm_src, 2 * N);

    k_scan1<<<B, 256, 0, stream>>>(cnt_in, row_ptr, partials, N);
    k_scan2<<<1, 64, 0, stream>>>(partials, B);
    k_scan3<<<B, 256, 0, stream>>>(row_ptr, partials, N);
    k_scatter<<<(E + 255) / 256, 256, 0, stream>>>(src, dst, row_ptr, cursor, csr, E);

    // layer 1: t = (x W1) * norm_src ; h = relu(agg * norm_dst + b1)
    k_gemm_mfma<128><<<(N + 63) / 64, 256, 0, stream>>>(x, W1, norm_src, t, N);
    k_agg<<<(N + 3) / 4, 256, 0, stream>>>(row_ptr, cnt_in, csr, t, norm_dst, b1, h, N, 1);

    // layer 2: t = (h W2) * norm_src ; out = agg * norm_dst + b2
    k_gemm_mfma<64><<<(N + 63) / 64, 256, 0, stream>>>(h, W2, norm_src, t, N);
    k_agg<<<(N + 3) / 4, 256, 0, stream>>>(row_ptr, cnt_in, csr, t, norm_dst, b2, out, N, 0);
}

// Round 6
// 384.694 us; speedup vs baseline: 2.9102x; 1.1532x over previous
//
#include <hip/hip_runtime.h>

#define D 64         // hidden/output feature dim
#define SLICE 25000  // degree-histogram nodes per slice (100 KB LDS)
#define NBUCK 512    // dst buckets (dst>>8), 391 used
#define EPB 4096     // edges per k_bin block

typedef __attribute__((ext_vector_type(8))) short short8;   // 8 bf16 (4 VGPRs)
typedef __attribute__((ext_vector_type(4))) float floatx4;  // 4 fp32 acc

// ---------------------------------------------------------------------------
// LDS-sliced degree histogram (R4 verbatim).
// ---------------------------------------------------------------------------
__global__ __launch_bounds__(256) void k_hist(const int* __restrict__ src,
                                              const int* __restrict__ dst,
                                              int* __restrict__ cnt_out,
                                              int* __restrict__ cnt_in,
                                              int E, int N) {
    __shared__ int h[SLICE];
    const int* idx = blockIdx.z ? dst : src;
    int* cnt       = blockIdx.z ? cnt_in : cnt_out;
    int lo = blockIdx.y * SLICE;
    int hi = min(lo + SLICE, N);
    int len = hi - lo;
    for (int i = threadIdx.x; i < len; i += 256) h[i] = 0;
    __syncthreads();

    const int E4 = E >> 2;
    const int4* idx4 = (const int4*)idx;
    int stride = gridDim.x * 256;
    for (int i = blockIdx.x * 256 + threadIdx.x; i < E4; i += stride) {
        int4 v = idx4[i];
        if (v.x >= lo && v.x < hi) atomicAdd(&h[v.x - lo], 1);
        if (v.y >= lo && v.y < hi) atomicAdd(&h[v.y - lo], 1);
        if (v.z >= lo && v.z < hi) atomicAdd(&h[v.z - lo], 1);
        if (v.w >= lo && v.w < hi) atomicAdd(&h[v.w - lo], 1);
    }
    if (blockIdx.x == 0) {
        int e = E4 * 4 + threadIdx.x;
        if (e < E) {
            int v = idx[e];
            if (v >= lo && v < hi) atomicAdd(&h[v - lo], 1);
        }
    }
    __syncthreads();
    for (int i = threadIdx.x; i < len; i += 256) {
        int c = h[i];
        if (c) atomicAdd(&cnt[lo + i], c);
    }
}

// ---- counts -> rsqrt(cnt + 1)  (the +1 is the self loop) ----
__global__ __launch_bounds__(256) void k_norm(const int* __restrict__ cnt,
                                              float* __restrict__ nrm, int n) {
    int i = blockIdx.x * 256 + threadIdx.x;
    if (i < n) nrm[i] = rsqrtf((float)cnt[i] + 1.0f);
}

// ---------------------------------------------------------------------------
// exclusive scan of cnt_in -> row_ptr  (R2/R4 verbatim)
// ---------------------------------------------------------------------------
__global__ __launch_bounds__(256) void k_scan1(const int* __restrict__ in,
                                               int* __restrict__ out,
                                               int* __restrict__ partials, int n) {
    __shared__ int s[256];
    int tid = threadIdx.x;
    int base = blockIdx.x * 1024 + tid * 4;
    int v[4];
#pragma unroll
    for (int j = 0; j < 4; ++j) v[j] = (base + j < n) ? in[base + j] : 0;
    int l1 = v[0] + v[1];
    int l2 = l1 + v[2];
    int total = l2 + v[3];
    s[tid] = total;
    __syncthreads();
    for (int off = 1; off < 256; off <<= 1) {
        int add = (tid >= off) ? s[tid - off] : 0;
        __syncthreads();
        s[tid] += add;
        __syncthreads();
    }
    int excl = s[tid] - total;
    if (base + 0 < n) out[base + 0] = excl;
    if (base + 1 < n) out[base + 1] = excl + v[0];
    if (base + 2 < n) out[base + 2] = excl + l1;
    if (base + 3 < n) out[base + 3] = excl + l2;
    if (tid == 255) partials[blockIdx.x] = s[255];
}

__global__ void k_scan2(int* __restrict__ partials, int B) {
    if (threadIdx.x == 0) {
        int run = 0;
        for (int i = 0; i < B; ++i) {
            int tmp = partials[i];
            partials[i] = run;
            run += tmp;
        }
    }
}

__global__ __launch_bounds__(256) void k_scan3(int* __restrict__ out,
                                               const int* __restrict__ partials, int n) {
    int off = partials[blockIdx.x];
    int base = blockIdx.x * 1024 + threadIdx.x * 4;
#pragma unroll
    for (int j = 0; j < 4; ++j)
        if (base + j < n) out[base + j] += off;
}

// ---------------------------------------------------------------------------
// Binned CSR build (replaces k_scatter):
//   k_bhist: 512-bucket histogram of dst>>8
//   k_bscan: 1-block exclusive scan -> bucket_base
//   k_bin:   per-block LDS counting sort into buckets; block-level reservation
//            via atomicAdd on memset-zeroed bucket_cursor (R2-proven pattern);
//            coalesced run writes of packed (dst,src) into binned[]
//   k_bsort: one block per bucket; LDS per-node cursors seeded from row_ptr;
//            scatter into the bucket's ~16KB csr window (stays in L2)
// ---------------------------------------------------------------------------
__global__ __launch_bounds__(256) void k_bhist(const int* __restrict__ dst,
                                               int* __restrict__ bucket_cnt, int E) {
    __shared__ int h[NBUCK];
    for (int i = threadIdx.x; i < NBUCK; i += 256) h[i] = 0;
    __syncthreads();
    const int E4 = E >> 2;
    const int4* d4 = (const int4*)dst;
    int stride = gridDim.x * 256;
    for (int i = blockIdx.x * 256 + threadIdx.x; i < E4; i += stride) {
        int4 v = d4[i];
        atomicAdd(&h[v.x >> 8], 1);
        atomicAdd(&h[v.y >> 8], 1);
        atomicAdd(&h[v.z >> 8], 1);
        atomicAdd(&h[v.w >> 8], 1);
    }
    if (blockIdx.x == 0) {
        int e = E4 * 4 + threadIdx.x;
        if (e < E) atomicAdd(&h[dst[e] >> 8], 1);
    }
    __syncthreads();
    for (int i = threadIdx.x; i < NBUCK; i += 256) {
        int c = h[i];
        if (c) atomicAdd(&bucket_cnt[i], c);
    }
}

__global__ __launch_bounds__(256) void k_bscan(const int* __restrict__ bucket_cnt,
                                               int* __restrict__ bucket_base) {
    __shared__ int s[256];
    int tid = threadIdx.x;
    int a = bucket_cnt[2 * tid];
    int b = bucket_cnt[2 * tid + 1];
    s[tid] = a + b;
    __syncthreads();
    for (int off = 1; off < 256; off <<= 1) {
        int add = (tid >= off) ? s[tid - off] : 0;
        __syncthreads();
        s[tid] += add;
        __syncthreads();
    }
    int excl = s[tid] - (a + b);
    bucket_base[2 * tid]     = excl;
    bucket_base[2 * tid + 1] = excl + a;
}

__global__ __launch_bounds__(256) void k_bin(const int* __restrict__ src,
                                             const int* __restrict__ dst,
                                             const int* __restrict__ bucket_base,
                                             int* __restrict__ bucket_cursor,
                                             unsigned long long* __restrict__ binned,
                                             int E) {
    __shared__ int cnt[NBUCK];
    __shared__ int bloc[NBUCK];   // local exclusive base (preserved)
    __shared__ int lcur[NBUCK];   // working cursor
    __shared__ int gbase[NBUCK];  // reserved global base
    __shared__ int ss[256];
    __shared__ unsigned long long stage[EPB];

    int tid = threadIdx.x;
    int start = blockIdx.x * EPB;
    int nloc = min(EPB, E - start);

    for (int i = tid; i < NBUCK; i += 256) cnt[i] = 0;
    __syncthreads();

    // phase 1: count buckets
#pragma unroll
    for (int r = 0; r < EPB / 256; ++r) {
        int idx = start + r * 256 + tid;
        if (idx < E) atomicAdd(&cnt[dst[idx] >> 8], 1);
    }
    __syncthreads();

    // LDS exclusive scan of cnt[512]
    int a = cnt[2 * tid], b = cnt[2 * tid + 1];
    ss[tid] = a + b;
    __syncthreads();
    for (int off = 1; off < 256; off <<= 1) {
        int add = (tid >= off) ? ss[tid - off] : 0;
        __syncthreads();
        ss[tid] += add;
        __syncthreads();
    }
    int excl = ss[tid] - (a + b);
    bloc[2 * tid] = excl;           lcur[2 * tid] = excl;
    bloc[2 * tid + 1] = excl + a;   lcur[2 * tid + 1] = excl + a;
    __syncthreads();

    // reservation: one atomic per (block, nonempty bucket)
    for (int bk = tid; bk < NBUCK; bk += 256) {
        int c = cnt[bk];
        gbase[bk] = c ? (atomicAdd(&bucket_cursor[bk], c) + bucket_base[bk]) : 0;
    }
    __syncthreads();

    // phase 2: stage into LDS in bucket-sorted order
#pragma unroll
    for (int r = 0; r < EPB / 256; ++r) {
        int idx = start + r * 256 + tid;
        if (idx < E) {
            int d = dst[idx];
            int p = atomicAdd(&lcur[d >> 8], 1);
            stage[p] = ((unsigned long long)(unsigned)d << 32) | (unsigned)src[idx];
        }
    }
    __syncthreads();

    // phase 3: coalesced run writes
#pragma unroll
    for (int r = 0; r < EPB / 256; ++r) {
        int i = r * 256 + tid;
        if (i < nloc) {
            unsigned long long e = stage[i];
            int bk = (int)(e >> 40);  // (dst >> 8): dst = e>>32, bucket = dst>>8
            binned[gbase[bk] + (i - bloc[bk])] = e;
        }
    }
}

__global__ __launch_bounds__(256) void k_bsort(const unsigned long long* __restrict__ binned,
                                               const int* __restrict__ bucket_base,
                                               const int* __restrict__ bucket_cnt,
                                               const int* __restrict__ row_ptr,
                                               int* __restrict__ csr, int N) {
    __shared__ int cur[256];
    int b = blockIdx.x;
    int n0 = b << 8;
    int tid = threadIdx.x;
    if (n0 + tid < N) cur[tid] = row_ptr[n0 + tid];
    __syncthreads();
    int base = bucket_base[b];
    int c = bucket_cnt[b];
    for (int k = tid; k < c; k += 256) {
        unsigned long long e = binned[base + k];
        int d = (int)(e >> 32);
        int s = (int)(e & 0xffffffffu);
        int p = atomicAdd(&cur[d - n0], 1);
        csr[p] = s;
    }
}

// ---------------------------------------------------------------------------
// MFMA dense layer via split-bf16 (R5 verbatim)
// ---------------------------------------------------------------------------
template <int K>
__global__ __launch_bounds__(256) void k_gemm_mfma(const float* __restrict__ hsrc,
                                                   const float* __restrict__ W,   // [K,64] row-major
                                                   const float* __restrict__ norm_src,
                                                   float* __restrict__ t, int N) {
    constexpr int NKI = K / 32;
    __shared__ short Whi[NKI * 2048];
    __shared__ short Wlo[NKI * 2048];
    int tid = threadIdx.x;

    for (int f = tid; f < K * 64; f += 256) {
        int n  = f & 15;
        int j  = (f >> 4) & 7;
        int q  = (f >> 7) & 3;
        int ct = (f >> 9) & 3;
        int ki = f >> 11;
        int k = ki * 32 + q * 8 + j;
        int c = ct * 16 + n;
        float w = W[k * 64 + c];
        unsigned u = __float_as_uint(w);
        float l = w - __uint_as_float(u & 0xffff0000u);
        int idx = (((ki * 4 + ct) * 16 + n) * 4 + q) * 8 + j;
        Whi[idx] = (short)(u >> 16);
        Wlo[idx] = (short)(__float_as_uint(l) >> 16);
    }
    __syncthreads();

    int wave = tid >> 6, lane = tid & 63;
    int q = lane >> 4, n = lane & 15;
    int r0 = blockIdx.x * 64 + wave * 16;
    int rowc = min(r0 + n, N - 1);

    floatx4 acc[4] = {{0.f,0.f,0.f,0.f},{0.f,0.f,0.f,0.f},
                      {0.f,0.f,0.f,0.f},{0.f,0.f,0.f,0.f}};

    for (int ki = 0; ki < NKI; ++ki) {
        const float* ap = hsrc + (long long)rowc * K + ki * 32 + q * 8;
        float4 a0 = *(const float4*)ap;
        float4 a1 = *(const float4*)(ap + 4);
        float av[8] = {a0.x, a0.y, a0.z, a0.w, a1.x, a1.y, a1.z, a1.w};
        short8 ahi, alo;
#pragma unroll
        for (int j = 0; j < 8; ++j) {
            unsigned u = __float_as_uint(av[j]);
            float l = av[j] - __uint_as_float(u & 0xffff0000u);
            ahi[j] = (short)(u >> 16);
            alo[j] = (short)(__float_as_uint(l) >> 16);
        }
#pragma unroll
        for (int ct = 0; ct < 4; ++ct) {
            int bidx = (((ki * 4 + ct) * 16 + n) * 4 + q) * 8;
            short8 bhi = *(const short8*)&Whi[bidx];
            short8 blo = *(const short8*)&Wlo[bidx];
            acc[ct] = __builtin_amdgcn_mfma_f32_16x16x32_bf16(ahi, bhi, acc[ct], 0, 0, 0);
            acc[ct] = __builtin_amdgcn_mfma_f32_16x16x32_bf16(ahi, blo, acc[ct], 0, 0, 0);
            acc[ct] = __builtin_amdgcn_mfma_f32_16x16x32_bf16(alo, bhi, acc[ct], 0, 0, 0);
        }
    }

#pragma unroll
    for (int reg = 0; reg < 4; ++reg) {
        int orow = r0 + q * 4 + reg;
        if (orow < N) {
            float nrm = norm_src[orow];
#pragma unroll
            for (int ct = 0; ct < 4; ++ct)
                t[(long long)orow * 64 + ct * 16 + n] = acc[ct][reg] * nrm;
        }
    }
}

// ---------------------------------------------------------------------------
// gather-aggregate + fused epilogue (R4 verbatim)
// ---------------------------------------------------------------------------
__global__ __launch_bounds__(256) void k_agg(const int* __restrict__ row_ptr,
                                             const int* __restrict__ cnt,
                                             const int* __restrict__ csr,
                                             const float* __restrict__ t,
                                             const float* __restrict__ norm_dst,
                                             const float* __restrict__ bias,
                                             float* __restrict__ out, int N, int do_relu) {
    int wave = threadIdx.x >> 6, lane = threadIdx.x & 63;
    int i = blockIdx.x * 4 + wave;
    if (i >= N) return;
    int start = row_ptr[i], c = cnt[i];
    float acc = t[i * D + lane];  // self loop
    int j = 0;
    for (; j + 4 <= c; j += 4) {
        int s0 = csr[start + j];
        int s1 = csr[start + j + 1];
        int s2 = csr[start + j + 2];
        int s3 = csr[start + j + 3];
        float a0 = t[s0 * D + lane];
        float a1 = t[s1 * D + lane];
        float a2 = t[s2 * D + lane];
        float a3 = t[s3 * D + lane];
        acc += (a0 + a1) + (a2 + a3);
    }
    for (; j < c; ++j) acc += t[csr[start + j] * D + lane];
    float v = fmaf(acc, norm_dst[i], bias[lane]);
    if (do_relu) v = fmaxf(v, 0.f);
    out[i * D + lane] = v;
}

extern "C" void kernel_launch(void* const* d_in, const int* in_sizes, int n_in,
                              void* d_out, int out_size, void* d_ws, size_t ws_size,
                              hipStream_t stream) {
    const float* x   = (const float*)d_in[0];
    const int*   src = (const int*)d_in[1];
    const int*   dst = (const int*)d_in[2];
    const float* W1  = (const float*)d_in[3];
    const float* b1  = (const float*)d_in[4];
    const float* W2  = (const float*)d_in[5];
    const float* b2  = (const float*)d_in[6];
    float* out = (float*)d_out;

    const int N = in_sizes[0] / 128;
    const int E = in_sizes[1];

    // workspace layout (4-byte units):
    int*   cnt_out  = (int*)d_ws;                // N
    int*   cnt_in   = cnt_out + N;               // N   (one memset covers both)
    int*   unused0  = cnt_in + N;                // N   (was cursor)
    int*   row_ptr  = unused0 + N;               // N
    int*   partials = row_ptr + N;               // 1024
    float* norm_src = (float*)(partials + 1024); // N
    float* norm_dst = norm_src + N;              // N
    float* t        = norm_dst + N;              // N*64
    float* h        = t + (long long)N * D;      // N*64
    int*   csr      = (int*)(h + (long long)N * D); // E
    int*   bucket_cnt    = csr + E;              // NBUCK
    int*   bucket_cursor = bucket_cnt + NBUCK;   // NBUCK (contiguous memset w/ cnt)
    int*   bucket_base   = bucket_cursor + NBUCK;// NBUCK
    // binned[] (E x 8B) aliases t (N*64*4 = 25.6MB >= E*8 = 12.8MB), free until gemm1
    unsigned long long* binned = (unsigned long long*)t;

    const int B = (N + 1023) / 1024;   // scan blocks
    const int NS = (N + SLICE - 1) / SLICE;
    const int NB = (N + 255) / 256;    // dst buckets in use
    const int NBK = (E + EPB - 1) / EPB;

    hipMemsetAsync(cnt_out, 0, (size_t)2 * N * sizeof(int), stream);
    hipMemsetAsync(bucket_cnt, 0, (size_t)2 * NBUCK * sizeof(int), stream);

    k_hist<<<dim3(32, NS, 2), 256, 0, stream>>>(src, dst, cnt_out, cnt_in, E, N);
    k_norm<<<(2 * N + 255) / 256, 256, 0, stream>>>(cnt_out, norm_src, 2 * N);

    k_scan1<<<B, 256, 0, stream>>>(cnt_in, row_ptr, partials, N);
    k_scan2<<<1, 64, 0, stream>>>(partials, B);
    k_scan3<<<B, 256, 0, stream>>>(row_ptr, partials, N);

    // binned CSR build
    k_bhist<<<64, 256, 0, stream>>>(dst, bucket_cnt, E);
    k_bscan<<<1, 256, 0, stream>>>(bucket_cnt, bucket_base);
    k_bin<<<NBK, 256, 0, stream>>>(src, dst, bucket_base, bucket_cursor, binned, E);
    k_bsort<<<NB, 256, 0, stream>>>(binned, bucket_base, bucket_cnt, row_ptr, csr, N);

    // layer 1: t = (x W1) * norm_src ; h = relu(agg * norm_dst + b1)
    k_gemm_mfma<128><<<(N + 63) / 64, 256, 0, stream>>>(x, W1, norm_src, t, N);
    k_agg<<<(N + 3) / 4, 256, 0, stream>>>(row_ptr, cnt_in, csr, t, norm_dst, b1, h, N, 1);

    // layer 2: t = (h W2) * norm_src ; out = agg * norm_dst + b2
    k_gemm_mfma<64><<<(N + 63) / 64, 256, 0, stream>>>(h, W2, norm_src, t, N);
    k_agg<<<(N + 3) / 4, 256, 0, stream>>>(row_ptr, cnt_in, csr, t, norm_dst, b2, out, N, 0);
}

// Round 7
// 366.797 us; speedup vs baseline: 3.0522x; 1.0488x over previous
//
#include <hip/hip_runtime.h>
#include <hip/hip_fp16.h>

#define D 64         // hidden/output feature dim
#define SLICE 25000  // degree-histogram nodes per slice (100 KB LDS)
#define NBUCK 512    // dst buckets (dst>>8), 391 used
#define EPB 4096     // edges per k_bin block

typedef __attribute__((ext_vector_type(8))) short short8;   // 8 bf16 (4 VGPRs)
typedef __attribute__((ext_vector_type(4))) float floatx4;  // 4 fp32 acc

// ---------------------------------------------------------------------------
// LDS-sliced degree histogram (R4 verbatim).
// ---------------------------------------------------------------------------
__global__ __launch_bounds__(256) void k_hist(const int* __restrict__ src,
                                              const int* __restrict__ dst,
                                              int* __restrict__ cnt_out,
                                              int* __restrict__ cnt_in,
                                              int E, int N) {
    __shared__ int h[SLICE];
    const int* idx = blockIdx.z ? dst : src;
    int* cnt       = blockIdx.z ? cnt_in : cnt_out;
    int lo = blockIdx.y * SLICE;
    int hi = min(lo + SLICE, N);
    int len = hi - lo;
    for (int i = threadIdx.x; i < len; i += 256) h[i] = 0;
    __syncthreads();

    const int E4 = E >> 2;
    const int4* idx4 = (const int4*)idx;
    int stride = gridDim.x * 256;
    for (int i = blockIdx.x * 256 + threadIdx.x; i < E4; i += stride) {
        int4 v = idx4[i];
        if (v.x >= lo && v.x < hi) atomicAdd(&h[v.x - lo], 1);
        if (v.y >= lo && v.y < hi) atomicAdd(&h[v.y - lo], 1);
        if (v.z >= lo && v.z < hi) atomicAdd(&h[v.z - lo], 1);
        if (v.w >= lo && v.w < hi) atomicAdd(&h[v.w - lo], 1);
    }
    if (blockIdx.x == 0) {
        int e = E4 * 4 + threadIdx.x;
        if (e < E) {
            int v = idx[e];
            if (v >= lo && v < hi) atomicAdd(&h[v - lo], 1);
        }
    }
    __syncthreads();
    for (int i = threadIdx.x; i < len; i += 256) {
        int c = h[i];
        if (c) atomicAdd(&cnt[lo + i], c);
    }
}

// ---- counts -> rsqrt(cnt + 1)  (the +1 is the self loop) ----
__global__ __launch_bounds__(256) void k_norm(const int* __restrict__ cnt,
                                              float* __restrict__ nrm, int n) {
    int i = blockIdx.x * 256 + threadIdx.x;
    if (i < n) nrm[i] = rsqrtf((float)cnt[i] + 1.0f);
}

// ---------------------------------------------------------------------------
// exclusive scan of cnt_in -> row_ptr  (R2/R4 verbatim)
// ---------------------------------------------------------------------------
__global__ __launch_bounds__(256) void k_scan1(const int* __restrict__ in,
                                               int* __restrict__ out,
                                               int* __restrict__ partials, int n) {
    __shared__ int s[256];
    int tid = threadIdx.x;
    int base = blockIdx.x * 1024 + tid * 4;
    int v[4];
#pragma unroll
    for (int j = 0; j < 4; ++j) v[j] = (base + j < n) ? in[base + j] : 0;
    int l1 = v[0] + v[1];
    int l2 = l1 + v[2];
    int total = l2 + v[3];
    s[tid] = total;
    __syncthreads();
    for (int off = 1; off < 256; off <<= 1) {
        int add = (tid >= off) ? s[tid - off] : 0;
        __syncthreads();
        s[tid] += add;
        __syncthreads();
    }
    int excl = s[tid] - total;
    if (base + 0 < n) out[base + 0] = excl;
    if (base + 1 < n) out[base + 1] = excl + v[0];
    if (base + 2 < n) out[base + 2] = excl + l1;
    if (base + 3 < n) out[base + 3] = excl + l2;
    if (tid == 255) partials[blockIdx.x] = s[255];
}

__global__ void k_scan2(int* __restrict__ partials, int B) {
    if (threadIdx.x == 0) {
        int run = 0;
        for (int i = 0; i < B; ++i) {
            int tmp = partials[i];
            partials[i] = run;
            run += tmp;
        }
    }
}

__global__ __launch_bounds__(256) void k_scan3(int* __restrict__ out,
                                               const int* __restrict__ partials, int n) {
    int off = partials[blockIdx.x];
    int base = blockIdx.x * 1024 + threadIdx.x * 4;
#pragma unroll
    for (int j = 0; j < 4; ++j)
        if (base + j < n) out[base + j] += off;
}

// ---------------------------------------------------------------------------
// Binned CSR build (R6 verbatim)
// ---------------------------------------------------------------------------
__global__ __launch_bounds__(256) void k_bhist(const int* __restrict__ dst,
                                               int* __restrict__ bucket_cnt, int E) {
    __shared__ int h[NBUCK];
    for (int i = threadIdx.x; i < NBUCK; i += 256) h[i] = 0;
    __syncthreads();
    const int E4 = E >> 2;
    const int4* d4 = (const int4*)dst;
    int stride = gridDim.x * 256;
    for (int i = blockIdx.x * 256 + threadIdx.x; i < E4; i += stride) {
        int4 v = d4[i];
        atomicAdd(&h[v.x >> 8], 1);
        atomicAdd(&h[v.y >> 8], 1);
        atomicAdd(&h[v.z >> 8], 1);
        atomicAdd(&h[v.w >> 8], 1);
    }
    if (blockIdx.x == 0) {
        int e = E4 * 4 + threadIdx.x;
        if (e < E) atomicAdd(&h[dst[e] >> 8], 1);
    }
    __syncthreads();
    for (int i = threadIdx.x; i < NBUCK; i += 256) {
        int c = h[i];
        if (c) atomicAdd(&bucket_cnt[i], c);
    }
}

__global__ __launch_bounds__(256) void k_bscan(const int* __restrict__ bucket_cnt,
                                               int* __restrict__ bucket_base) {
    __shared__ int s[256];
    int tid = threadIdx.x;
    int a = bucket_cnt[2 * tid];
    int b = bucket_cnt[2 * tid + 1];
    s[tid] = a + b;
    __syncthreads();
    for (int off = 1; off < 256; off <<= 1) {
        int add = (tid >= off) ? s[tid - off] : 0;
        __syncthreads();
        s[tid] += add;
        __syncthreads();
    }
    int excl = s[tid] - (a + b);
    bucket_base[2 * tid]     = excl;
    bucket_base[2 * tid + 1] = excl + a;
}

__global__ __launch_bounds__(256) void k_bin(const int* __restrict__ src,
                                             const int* __restrict__ dst,
                                             const int* __restrict__ bucket_base,
                                             int* __restrict__ bucket_cursor,
                                             unsigned long long* __restrict__ binned,
                                             int E) {
    __shared__ int cnt[NBUCK];
    __shared__ int bloc[NBUCK];
    __shared__ int lcur[NBUCK];
    __shared__ int gbase[NBUCK];
    __shared__ int ss[256];
    __shared__ unsigned long long stage[EPB];

    int tid = threadIdx.x;
    int start = blockIdx.x * EPB;
    int nloc = min(EPB, E - start);

    for (int i = tid; i < NBUCK; i += 256) cnt[i] = 0;
    __syncthreads();

#pragma unroll
    for (int r = 0; r < EPB / 256; ++r) {
        int idx = start + r * 256 + tid;
        if (idx < E) atomicAdd(&cnt[dst[idx] >> 8], 1);
    }
    __syncthreads();

    int a = cnt[2 * tid], b = cnt[2 * tid + 1];
    ss[tid] = a + b;
    __syncthreads();
    for (int off = 1; off < 256; off <<= 1) {
        int add = (tid >= off) ? ss[tid - off] : 0;
        __syncthreads();
        ss[tid] += add;
        __syncthreads();
    }
    int excl = ss[tid] - (a + b);
    bloc[2 * tid] = excl;           lcur[2 * tid] = excl;
    bloc[2 * tid + 1] = excl + a;   lcur[2 * tid + 1] = excl + a;
    __syncthreads();

    for (int bk = tid; bk < NBUCK; bk += 256) {
        int c = cnt[bk];
        gbase[bk] = c ? (atomicAdd(&bucket_cursor[bk], c) + bucket_base[bk]) : 0;
    }
    __syncthreads();

#pragma unroll
    for (int r = 0; r < EPB / 256; ++r) {
        int idx = start + r * 256 + tid;
        if (idx < E) {
            int d = dst[idx];
            int p = atomicAdd(&lcur[d >> 8], 1);
            stage[p] = ((unsigned long long)(unsigned)d << 32) | (unsigned)src[idx];
        }
    }
    __syncthreads();

#pragma unroll
    for (int r = 0; r < EPB / 256; ++r) {
        int i = r * 256 + tid;
        if (i < nloc) {
            unsigned long long e = stage[i];
            int bk = (int)(e >> 40);
            binned[gbase[bk] + (i - bloc[bk])] = e;
        }
    }
}

__global__ __launch_bounds__(256) void k_bsort(const unsigned long long* __restrict__ binned,
                                               const int* __restrict__ bucket_base,
                                               const int* __restrict__ bucket_cnt,
                                               const int* __restrict__ row_ptr,
                                               int* __restrict__ csr, int N) {
    __shared__ int cur[256];
    int b = blockIdx.x;
    int n0 = b << 8;
    int tid = threadIdx.x;
    if (n0 + tid < N) cur[tid] = row_ptr[n0 + tid];
    __syncthreads();
    int base = bucket_base[b];
    int c = bucket_cnt[b];
    for (int k = tid; k < c; k += 256) {
        unsigned long long e = binned[base + k];
        int d = (int)(e >> 32);
        int s = (int)(e & 0xffffffffu);
        int p = atomicAdd(&cur[d - n0], 1);
        csr[p] = s;
    }
}

// ---------------------------------------------------------------------------
// MFMA dense layer via split-bf16 (R5 structure); epilogue now emits fp16.
// ---------------------------------------------------------------------------
template <int K>
__global__ __launch_bounds__(256) void k_gemm_mfma(const float* __restrict__ hsrc,
                                                   const float* __restrict__ W,   // [K,64] row-major
                                                   const float* __restrict__ norm_src,
                                                   __half* __restrict__ t, int N) {
    constexpr int NKI = K / 32;
    __shared__ short Whi[NKI * 2048];
    __shared__ short Wlo[NKI * 2048];
    int tid = threadIdx.x;

    for (int f = tid; f < K * 64; f += 256) {
        int n  = f & 15;
        int j  = (f >> 4) & 7;
        int q  = (f >> 7) & 3;
        int ct = (f >> 9) & 3;
        int ki = f >> 11;
        int k = ki * 32 + q * 8 + j;
        int c = ct * 16 + n;
        float w = W[k * 64 + c];
        unsigned u = __float_as_uint(w);
        float l = w - __uint_as_float(u & 0xffff0000u);
        int idx = (((ki * 4 + ct) * 16 + n) * 4 + q) * 8 + j;
        Whi[idx] = (short)(u >> 16);
        Wlo[idx] = (short)(__float_as_uint(l) >> 16);
    }
    __syncthreads();

    int wave = tid >> 6, lane = tid & 63;
    int q = lane >> 4, n = lane & 15;
    int r0 = blockIdx.x * 64 + wave * 16;
    int rowc = min(r0 + n, N - 1);

    floatx4 acc[4] = {{0.f,0.f,0.f,0.f},{0.f,0.f,0.f,0.f},
                      {0.f,0.f,0.f,0.f},{0.f,0.f,0.f,0.f}};

    for (int ki = 0; ki < NKI; ++ki) {
        const float* ap = hsrc + (long long)rowc * K + ki * 32 + q * 8;
        float4 a0 = *(const float4*)ap;
        float4 a1 = *(const float4*)(ap + 4);
        float av[8] = {a0.x, a0.y, a0.z, a0.w, a1.x, a1.y, a1.z, a1.w};
        short8 ahi, alo;
#pragma unroll
        for (int j = 0; j < 8; ++j) {
            unsigned u = __float_as_uint(av[j]);
            float l = av[j] - __uint_as_float(u & 0xffff0000u);
            ahi[j] = (short)(u >> 16);
            alo[j] = (short)(__float_as_uint(l) >> 16);
        }
#pragma unroll
        for (int ct = 0; ct < 4; ++ct) {
            int bidx = (((ki * 4 + ct) * 16 + n) * 4 + q) * 8;
            short8 bhi = *(const short8*)&Whi[bidx];
            short8 blo = *(const short8*)&Wlo[bidx];
            acc[ct] = __builtin_amdgcn_mfma_f32_16x16x32_bf16(ahi, bhi, acc[ct], 0, 0, 0);
            acc[ct] = __builtin_amdgcn_mfma_f32_16x16x32_bf16(ahi, blo, acc[ct], 0, 0, 0);
            acc[ct] = __builtin_amdgcn_mfma_f32_16x16x32_bf16(alo, bhi, acc[ct], 0, 0, 0);
        }
    }

#pragma unroll
    for (int reg = 0; reg < 4; ++reg) {
        int orow = r0 + q * 4 + reg;
        if (orow < N) {
            float nrm = norm_src[orow];
#pragma unroll
            for (int ct = 0; ct < 4; ++ct)
                t[(long long)orow * 64 + ct * 16 + n] = __float2half(acc[ct][reg] * nrm);
        }
    }
}

// ---------------------------------------------------------------------------
// gather-aggregate + fused epilogue; messages now fp16 (128 B/edge gather).
// Accumulation stays fp32.
// ---------------------------------------------------------------------------
__global__ __launch_bounds__(256) void k_agg(const int* __restrict__ row_ptr,
                                             const int* __restrict__ cnt,
                                             const int* __restrict__ csr,
                                             const __half* __restrict__ t,
                                             const float* __restrict__ norm_dst,
                                             const float* __restrict__ bias,
                                             float* __restrict__ out, int N, int do_relu) {
    int wave = threadIdx.x >> 6, lane = threadIdx.x & 63;
    int i = blockIdx.x * 4 + wave;
    if (i >= N) return;
    int start = row_ptr[i], c = cnt[i];
    float acc = __half2float(t[i * D + lane]);  // self loop
    int j = 0;
    for (; j + 4 <= c; j += 4) {
        int s0 = csr[start + j];
        int s1 = csr[start + j + 1];
        int s2 = csr[start + j + 2];
        int s3 = csr[start + j + 3];
        float a0 = __half2float(t[s0 * D + lane]);
        float a1 = __half2float(t[s1 * D + lane]);
        float a2 = __half2float(t[s2 * D + lane]);
        float a3 = __half2float(t[s3 * D + lane]);
        acc += (a0 + a1) + (a2 + a3);
    }
    for (; j < c; ++j) acc += __half2float(t[csr[start + j] * D + lane]);
    float v = fmaf(acc, norm_dst[i], bias[lane]);
    if (do_relu) v = fmaxf(v, 0.f);
    out[i * D + lane] = v;
}

extern "C" void kernel_launch(void* const* d_in, const int* in_sizes, int n_in,
                              void* d_out, int out_size, void* d_ws, size_t ws_size,
                              hipStream_t stream) {
    const float* x   = (const float*)d_in[0];
    const int*   src = (const int*)d_in[1];
    const int*   dst = (const int*)d_in[2];
    const float* W1  = (const float*)d_in[3];
    const float* b1  = (const float*)d_in[4];
    const float* W2  = (const float*)d_in[5];
    const float* b2  = (const float*)d_in[6];
    float* out = (float*)d_out;

    const int N = in_sizes[0] / 128;
    const int E = in_sizes[1];

    // workspace layout (4-byte units) — same region map as R6; t holds fp16 now
    int*   cnt_out  = (int*)d_ws;                // N
    int*   cnt_in   = cnt_out + N;               // N   (one memset covers both)
    int*   unused0  = cnt_in + N;                // N
    int*   row_ptr  = unused0 + N;               // N
    int*   partials = row_ptr + N;               // 1024
    float* norm_src = (float*)(partials + 1024); // N
    float* norm_dst = norm_src + N;              // N
    float* tbase    = norm_dst + N;              // N*64 fp32 region (fp16 uses half)
    float* h        = tbase + (long long)N * D;  // N*64 fp32
    int*   csr      = (int*)(h + (long long)N * D); // E
    int*   bucket_cnt    = csr + E;              // NBUCK
    int*   bucket_cursor = bucket_cnt + NBUCK;   // NBUCK
    int*   bucket_base   = bucket_cursor + NBUCK;// NBUCK
    __half* t_h = (__half*)tbase;
    // binned[] (E x 8B = 12.8MB) aliases tbase region (25.6MB), dead before gemm1
    unsigned long long* binned = (unsigned long long*)tbase;

    const int B = (N + 1023) / 1024;
    const int NS = (N + SLICE - 1) / SLICE;
    const int NB = (N + 255) / 256;
    const int NBK = (E + EPB - 1) / EPB;

    hipMemsetAsync(cnt_out, 0, (size_t)2 * N * sizeof(int), stream);
    hipMemsetAsync(bucket_cnt, 0, (size_t)2 * NBUCK * sizeof(int), stream);

    k_hist<<<dim3(32, NS, 2), 256, 0, stream>>>(src, dst, cnt_out, cnt_in, E, N);
    k_norm<<<(2 * N + 255) / 256, 256, 0, stream>>>(cnt_out, norm_src, 2 * N);

    k_scan1<<<B, 256, 0, stream>>>(cnt_in, row_ptr, partials, N);
    k_scan2<<<1, 64, 0, stream>>>(partials, B);
    k_scan3<<<B, 256, 0, stream>>>(row_ptr, partials, N);

    k_bhist<<<64, 256, 0, stream>>>(dst, bucket_cnt, E);
    k_bscan<<<1, 256, 0, stream>>>(bucket_cnt, bucket_base);
    k_bin<<<NBK, 256, 0, stream>>>(src, dst, bucket_base, bucket_cursor, binned, E);
    k_bsort<<<NB, 256, 0, stream>>>(binned, bucket_base, bucket_cnt, row_ptr, csr, N);

    // layer 1: t = (x W1) * norm_src ; h = relu(agg * norm_dst + b1)
    k_gemm_mfma<128><<<(N + 63) / 64, 256, 0, stream>>>(x, W1, norm_src, t_h, N);
    k_agg<<<(N + 3) / 4, 256, 0, stream>>>(row_ptr, cnt_in, csr, t_h, norm_dst, b1, h, N, 1);

    // layer 2: t = (h W2) * norm_src ; out = agg * norm_dst + b2
    k_gemm_mfma<64><<<(N + 63) / 64, 256, 0, stream>>>(h, W2, norm_src, t_h, N);
    k_agg<<<(N + 3) / 4, 256, 0, stream>>>(row_ptr, cnt_in, csr, t_h, norm_dst, b2, out, N, 0);
}

// Round 8
// 336.552 us; speedup vs baseline: 3.3265x; 1.0899x over previous
//
#include <hip/hip_runtime.h>
#include <hip/hip_fp16.h>

#define D 64         // hidden/output feature dim
#define SLICE 25000  // degree-histogram nodes per slice (100 KB LDS)
#define NBUCK 512    // dst buckets (dst>>8), 391 used
#define EPB 4096     // edges per k_bin block

typedef __attribute__((ext_vector_type(8))) short short8;   // 8 bf16 (4 VGPRs)
typedef __attribute__((ext_vector_type(4))) float floatx4;  // 4 fp32 acc

// ---------------------------------------------------------------------------
// LDS-sliced degree histogram (R4 verbatim).
// ---------------------------------------------------------------------------
__global__ __launch_bounds__(256) void k_hist(const int* __restrict__ src,
                                              const int* __restrict__ dst,
                                              int* __restrict__ cnt_out,
                                              int* __restrict__ cnt_in,
                                              int E, int N) {
    __shared__ int h[SLICE];
    const int* idx = blockIdx.z ? dst : src;
    int* cnt       = blockIdx.z ? cnt_in : cnt_out;
    int lo = blockIdx.y * SLICE;
    int hi = min(lo + SLICE, N);
    int len = hi - lo;
    for (int i = threadIdx.x; i < len; i += 256) h[i] = 0;
    __syncthreads();

    const int E4 = E >> 2;
    const int4* idx4 = (const int4*)idx;
    int stride = gridDim.x * 256;
    for (int i = blockIdx.x * 256 + threadIdx.x; i < E4; i += stride) {
        int4 v = idx4[i];
        if (v.x >= lo && v.x < hi) atomicAdd(&h[v.x - lo], 1);
        if (v.y >= lo && v.y < hi) atomicAdd(&h[v.y - lo], 1);
        if (v.z >= lo && v.z < hi) atomicAdd(&h[v.z - lo], 1);
        if (v.w >= lo && v.w < hi) atomicAdd(&h[v.w - lo], 1);
    }
    if (blockIdx.x == 0) {
        int e = E4 * 4 + threadIdx.x;
        if (e < E) {
            int v = idx[e];
            if (v >= lo && v < hi) atomicAdd(&h[v - lo], 1);
        }
    }
    __syncthreads();
    for (int i = threadIdx.x; i < len; i += 256) {
        int c = h[i];
        if (c) atomicAdd(&cnt[lo + i], c);
    }
}

// ---- counts -> rsqrt(cnt + 1)  (the +1 is the self loop) ----
__global__ __launch_bounds__(256) void k_norm(const int* __restrict__ cnt,
                                              float* __restrict__ nrm, int n) {
    int i = blockIdx.x * 256 + threadIdx.x;
    if (i < n) nrm[i] = rsqrtf((float)cnt[i] + 1.0f);
}

// ---------------------------------------------------------------------------
// exclusive scan of cnt_in -> row_ptr  (R2/R4 verbatim)
// ---------------------------------------------------------------------------
__global__ __launch_bounds__(256) void k_scan1(const int* __restrict__ in,
                                               int* __restrict__ out,
                                               int* __restrict__ partials, int n) {
    __shared__ int s[256];
    int tid = threadIdx.x;
    int base = blockIdx.x * 1024 + tid * 4;
    int v[4];
#pragma unroll
    for (int j = 0; j < 4; ++j) v[j] = (base + j < n) ? in[base + j] : 0;
    int l1 = v[0] + v[1];
    int l2 = l1 + v[2];
    int total = l2 + v[3];
    s[tid] = total;
    __syncthreads();
    for (int off = 1; off < 256; off <<= 1) {
        int add = (tid >= off) ? s[tid - off] : 0;
        __syncthreads();
        s[tid] += add;
        __syncthreads();
    }
    int excl = s[tid] - total;
    if (base + 0 < n) out[base + 0] = excl;
    if (base + 1 < n) out[base + 1] = excl + v[0];
    if (base + 2 < n) out[base + 2] = excl + l1;
    if (base + 3 < n) out[base + 3] = excl + l2;
    if (tid == 255) partials[blockIdx.x] = s[255];
}

__global__ void k_scan2(int* __restrict__ partials, int B) {
    if (threadIdx.x == 0) {
        int run = 0;
        for (int i = 0; i < B; ++i) {
            int tmp = partials[i];
            partials[i] = run;
            run += tmp;
        }
    }
}

__global__ __launch_bounds__(256) void k_scan3(int* __restrict__ out,
                                               const int* __restrict__ partials, int n) {
    int off = partials[blockIdx.x];
    int base = blockIdx.x * 1024 + threadIdx.x * 4;
#pragma unroll
    for (int j = 0; j < 4; ++j)
        if (base + j < n) out[base + j] += off;
}

// ---------------------------------------------------------------------------
// Binned CSR build (R6 verbatim)
// ---------------------------------------------------------------------------
__global__ __launch_bounds__(256) void k_bhist(const int* __restrict__ dst,
                                               int* __restrict__ bucket_cnt, int E) {
    __shared__ int h[NBUCK];
    for (int i = threadIdx.x; i < NBUCK; i += 256) h[i] = 0;
    __syncthreads();
    const int E4 = E >> 2;
    const int4* d4 = (const int4*)dst;
    int stride = gridDim.x * 256;
    for (int i = blockIdx.x * 256 + threadIdx.x; i < E4; i += stride) {
        int4 v = d4[i];
        atomicAdd(&h[v.x >> 8], 1);
        atomicAdd(&h[v.y >> 8], 1);
        atomicAdd(&h[v.z >> 8], 1);
        atomicAdd(&h[v.w >> 8], 1);
    }
    if (blockIdx.x == 0) {
        int e = E4 * 4 + threadIdx.x;
        if (e < E) atomicAdd(&h[dst[e] >> 8], 1);
    }
    __syncthreads();
    for (int i = threadIdx.x; i < NBUCK; i += 256) {
        int c = h[i];
        if (c) atomicAdd(&bucket_cnt[i], c);
    }
}

__global__ __launch_bounds__(256) void k_bscan(const int* __restrict__ bucket_cnt,
                                               int* __restrict__ bucket_base) {
    __shared__ int s[256];
    int tid = threadIdx.x;
    int a = bucket_cnt[2 * tid];
    int b = bucket_cnt[2 * tid + 1];
    s[tid] = a + b;
    __syncthreads();
    for (int off = 1; off < 256; off <<= 1) {
        int add = (tid >= off) ? s[tid - off] : 0;
        __syncthreads();
        s[tid] += add;
        __syncthreads();
    }
    int excl = s[tid] - (a + b);
    bucket_base[2 * tid]     = excl;
    bucket_base[2 * tid + 1] = excl + a;
}

__global__ __launch_bounds__(256) void k_bin(const int* __restrict__ src,
                                             const int* __restrict__ dst,
                                             const int* __restrict__ bucket_base,
                                             int* __restrict__ bucket_cursor,
                                             unsigned long long* __restrict__ binned,
                                             int E) {
    __shared__ int cnt[NBUCK];
    __shared__ int bloc[NBUCK];
    __shared__ int lcur[NBUCK];
    __shared__ int gbase[NBUCK];
    __shared__ int ss[256];
    __shared__ unsigned long long stage[EPB];

    int tid = threadIdx.x;
    int start = blockIdx.x * EPB;
    int nloc = min(EPB, E - start);

    for (int i = tid; i < NBUCK; i += 256) cnt[i] = 0;
    __syncthreads();

#pragma unroll
    for (int r = 0; r < EPB / 256; ++r) {
        int idx = start + r * 256 + tid;
        if (idx < E) atomicAdd(&cnt[dst[idx] >> 8], 1);
    }
    __syncthreads();

    int a = cnt[2 * tid], b = cnt[2 * tid + 1];
    ss[tid] = a + b;
    __syncthreads();
    for (int off = 1; off < 256; off <<= 1) {
        int add = (tid >= off) ? ss[tid - off] : 0;
        __syncthreads();
        ss[tid] += add;
        __syncthreads();
    }
    int excl = ss[tid] - (a + b);
    bloc[2 * tid] = excl;           lcur[2 * tid] = excl;
    bloc[2 * tid + 1] = excl + a;   lcur[2 * tid + 1] = excl + a;
    __syncthreads();

    for (int bk = tid; bk < NBUCK; bk += 256) {
        int c = cnt[bk];
        gbase[bk] = c ? (atomicAdd(&bucket_cursor[bk], c) + bucket_base[bk]) : 0;
    }
    __syncthreads();

#pragma unroll
    for (int r = 0; r < EPB / 256; ++r) {
        int idx = start + r * 256 + tid;
        if (idx < E) {
            int d = dst[idx];
            int p = atomicAdd(&lcur[d >> 8], 1);
            stage[p] = ((unsigned long long)(unsigned)d << 32) | (unsigned)src[idx];
        }
    }
    __syncthreads();

#pragma unroll
    for (int r = 0; r < EPB / 256; ++r) {
        int i = r * 256 + tid;
        if (i < nloc) {
            unsigned long long e = stage[i];
            int bk = (int)(e >> 40);
            binned[gbase[bk] + (i - bloc[bk])] = e;
        }
    }
}

__global__ __launch_bounds__(256) void k_bsort(const unsigned long long* __restrict__ binned,
                                               const int* __restrict__ bucket_base,
                                               const int* __restrict__ bucket_cnt,
                                               const int* __restrict__ row_ptr,
                                               int* __restrict__ csr, int N) {
    __shared__ int cur[256];
    int b = blockIdx.x;
    int n0 = b << 8;
    int tid = threadIdx.x;
    if (n0 + tid < N) cur[tid] = row_ptr[n0 + tid];
    __syncthreads();
    int base = bucket_base[b];
    int c = bucket_cnt[b];
    for (int k = tid; k < c; k += 256) {
        unsigned long long e = binned[base + k];
        int d = (int)(e >> 32);
        int s = (int)(e & 0xffffffffu);
        int p = atomicAdd(&cur[d - n0], 1);
        csr[p] = s;
    }
}

// ---------------------------------------------------------------------------
// MFMA dense layer via split-bf16 (R7 verbatim, fp16 epilogue)
// ---------------------------------------------------------------------------
template <int K>
__global__ __launch_bounds__(256) void k_gemm_mfma(const float* __restrict__ hsrc,
                                                   const float* __restrict__ W,   // [K,64] row-major
                                                   const float* __restrict__ norm_src,
                                                   __half* __restrict__ t, int N) {
    constexpr int NKI = K / 32;
    __shared__ short Whi[NKI * 2048];
    __shared__ short Wlo[NKI * 2048];
    int tid = threadIdx.x;

    for (int f = tid; f < K * 64; f += 256) {
        int n  = f & 15;
        int j  = (f >> 4) & 7;
        int q  = (f >> 7) & 3;
        int ct = (f >> 9) & 3;
        int ki = f >> 11;
        int k = ki * 32 + q * 8 + j;
        int c = ct * 16 + n;
        float w = W[k * 64 + c];
        unsigned u = __float_as_uint(w);
        float l = w - __uint_as_float(u & 0xffff0000u);
        int idx = (((ki * 4 + ct) * 16 + n) * 4 + q) * 8 + j;
        Whi[idx] = (short)(u >> 16);
        Wlo[idx] = (short)(__float_as_uint(l) >> 16);
    }
    __syncthreads();

    int wave = tid >> 6, lane = tid & 63;
    int q = lane >> 4, n = lane & 15;
    int r0 = blockIdx.x * 64 + wave * 16;
    int rowc = min(r0 + n, N - 1);

    floatx4 acc[4] = {{0.f,0.f,0.f,0.f},{0.f,0.f,0.f,0.f},
                      {0.f,0.f,0.f,0.f},{0.f,0.f,0.f,0.f}};

    for (int ki = 0; ki < NKI; ++ki) {
        const float* ap = hsrc + (long long)rowc * K + ki * 32 + q * 8;
        float4 a0 = *(const float4*)ap;
        float4 a1 = *(const float4*)(ap + 4);
        float av[8] = {a0.x, a0.y, a0.z, a0.w, a1.x, a1.y, a1.z, a1.w};
        short8 ahi, alo;
#pragma unroll
        for (int j = 0; j < 8; ++j) {
            unsigned u = __float_as_uint(av[j]);
            float l = av[j] - __uint_as_float(u & 0xffff0000u);
            ahi[j] = (short)(u >> 16);
            alo[j] = (short)(__float_as_uint(l) >> 16);
        }
#pragma unroll
        for (int ct = 0; ct < 4; ++ct) {
            int bidx = (((ki * 4 + ct) * 16 + n) * 4 + q) * 8;
            short8 bhi = *(const short8*)&Whi[bidx];
            short8 blo = *(const short8*)&Wlo[bidx];
            acc[ct] = __builtin_amdgcn_mfma_f32_16x16x32_bf16(ahi, bhi, acc[ct], 0, 0, 0);
            acc[ct] = __builtin_amdgcn_mfma_f32_16x16x32_bf16(ahi, blo, acc[ct], 0, 0, 0);
            acc[ct] = __builtin_amdgcn_mfma_f32_16x16x32_bf16(alo, bhi, acc[ct], 0, 0, 0);
        }
    }

#pragma unroll
    for (int reg = 0; reg < 4; ++reg) {
        int orow = r0 + q * 4 + reg;
        if (orow < N) {
            float nrm = norm_src[orow];
#pragma unroll
            for (int ct = 0; ct < 4; ++ct)
                t[(long long)orow * 64 + ct * 16 + n] = __float2half(acc[ct][reg] * nrm);
        }
    }
}

// ---------------------------------------------------------------------------
// gather-aggregate v2: wave = 2 nodes (32 lanes each); lane = channel-pair
// (half2, 4B/lane).  One gather instruction covers 2 edges' 128B rows;
// csr neighbor lists read as aligned int4.  fp32 accumulation.
// ---------------------------------------------------------------------------
__global__ __launch_bounds__(256) void k_agg(const int* __restrict__ row_ptr,
                                             const int* __restrict__ cnt,
                                             const int* __restrict__ csr,
                                             const __half* __restrict__ t,
                                             const float* __restrict__ norm_dst,
                                             const float* __restrict__ bias,
                                             float* __restrict__ out, int N, int do_relu) {
    int tid = threadIdx.x;
    int half_id = tid >> 5;      // 0..7: node slot within block
    int lane = tid & 31;         // channel pair
    int i = blockIdx.x * 8 + half_id;
    if (i >= N) return;
    const __half2* t2 = (const __half2*)t;
    int start = row_ptr[i], c = cnt[i];

    __half2 self = t2[i * 32 + lane];
    float2 sf = __half22float2(self);
    float ax = sf.x, ay = sf.y;

    int j = 0;
    int pre = min(c, (4 - (start & 3)) & 3);   // align csr pointer to 16B
    for (; j < pre; ++j) {
        float2 f = __half22float2(t2[csr[start + j] * 32 + lane]);
        ax += f.x; ay += f.y;
    }
    for (; j + 4 <= c; j += 4) {
        int4 s4 = *(const int4*)&csr[start + j];
        float2 f0 = __half22float2(t2[s4.x * 32 + lane]);
        float2 f1 = __half22float2(t2[s4.y * 32 + lane]);
        float2 f2 = __half22float2(t2[s4.z * 32 + lane]);
        float2 f3 = __half22float2(t2[s4.w * 32 + lane]);
        ax += (f0.x + f1.x) + (f2.x + f3.x);
        ay += (f0.y + f1.y) + (f2.y + f3.y);
    }
    for (; j < c; ++j) {
        float2 f = __half22float2(t2[csr[start + j] * 32 + lane]);
        ax += f.x; ay += f.y;
    }

    float nrm = norm_dst[i];
    float2 bb = ((const float2*)bias)[lane];
    float vx = fmaf(ax, nrm, bb.x);
    float vy = fmaf(ay, nrm, bb.y);
    if (do_relu) { vx = fmaxf(vx, 0.f); vy = fmaxf(vy, 0.f); }
    float2 o; o.x = vx; o.y = vy;
    ((float2*)out)[i * 32 + lane] = o;
}

extern "C" void kernel_launch(void* const* d_in, const int* in_sizes, int n_in,
                              void* d_out, int out_size, void* d_ws, size_t ws_size,
                              hipStream_t stream) {
    const float* x   = (const float*)d_in[0];
    const int*   src = (const int*)d_in[1];
    const int*   dst = (const int*)d_in[2];
    const float* W1  = (const float*)d_in[3];
    const float* b1  = (const float*)d_in[4];
    const float* W2  = (const float*)d_in[5];
    const float* b2  = (const float*)d_in[6];
    float* out = (float*)d_out;

    const int N = in_sizes[0] / 128;
    const int E = in_sizes[1];

    // workspace layout (4-byte units) — same region map as R7
    int*   cnt_out  = (int*)d_ws;                // N
    int*   cnt_in   = cnt_out + N;               // N   (one memset covers both)
    int*   unused0  = cnt_in + N;                // N
    int*   row_ptr  = unused0 + N;               // N
    int*   partials = row_ptr + N;               // 1024
    float* norm_src = (float*)(partials + 1024); // N
    float* norm_dst = norm_src + N;              // N
    float* tbase    = norm_dst + N;              // N*64 fp32 region (fp16 uses half)
    float* h        = tbase + (long long)N * D;  // N*64 fp32
    int*   csr      = (int*)(h + (long long)N * D); // E
    int*   bucket_cnt    = csr + E;              // NBUCK
    int*   bucket_cursor = bucket_cnt + NBUCK;   // NBUCK
    int*   bucket_base   = bucket_cursor + NBUCK;// NBUCK
    __half* t_h = (__half*)tbase;
    unsigned long long* binned = (unsigned long long*)tbase;  // dead before gemm1

    const int B = (N + 1023) / 1024;
    const int NS = (N + SLICE - 1) / SLICE;
    const int NB = (N + 255) / 256;
    const int NBK = (E + EPB - 1) / EPB;

    hipMemsetAsync(cnt_out, 0, (size_t)2 * N * sizeof(int), stream);
    hipMemsetAsync(bucket_cnt, 0, (size_t)2 * NBUCK * sizeof(int), stream);

    k_hist<<<dim3(32, NS, 2), 256, 0, stream>>>(src, dst, cnt_out, cnt_in, E, N);
    k_norm<<<(2 * N + 255) / 256, 256, 0, stream>>>(cnt_out, norm_src, 2 * N);

    k_scan1<<<B, 256, 0, stream>>>(cnt_in, row_ptr, partials, N);
    k_scan2<<<1, 64, 0, stream>>>(partials, B);
    k_scan3<<<B, 256, 0, stream>>>(row_ptr, partials, N);

    k_bhist<<<64, 256, 0, stream>>>(dst, bucket_cnt, E);
    k_bscan<<<1, 256, 0, stream>>>(bucket_cnt, bucket_base);
    k_bin<<<NBK, 256, 0, stream>>>(src, dst, bucket_base, bucket_cursor, binned, E);
    k_bsort<<<NB, 256, 0, stream>>>(binned, bucket_base, bucket_cnt, row_ptr, csr, N);

    // layer 1: t = (x W1) * norm_src ; h = relu(agg * norm_dst + b1)
    k_gemm_mfma<128><<<(N + 63) / 64, 256, 0, stream>>>(x, W1, norm_src, t_h, N);
    k_agg<<<(N + 7) / 8, 256, 0, stream>>>(row_ptr, cnt_in, csr, t_h, norm_dst, b1, h, N, 1);

    // layer 2: t = (h W2) * norm_src ; out = agg * norm_dst + b2
    k_gemm_mfma<64><<<(N + 63) / 64, 256, 0, stream>>>(h, W2, norm_src, t_h, N);
    k_agg<<<(N + 7) / 8, 256, 0, stream>>>(row_ptr, cnt_in, csr, t_h, norm_dst, b2, out, N, 0);
}